// Round 1
// baseline (96.212 us; speedup 1.0000x reference)
//
#include <hip/hip_runtime.h>

#define D 128
#define MARGIN 1.0f
#define EPS 1e-6f

// One wave (64 lanes) per triple-pair: lanes 0-31 = pos triple, lanes 32-63 = neg triple.
// Each lane holds a float4 slice (l = lane&31) of every 128-float row.
__global__ __launch_bounds__(256, 8) void transd_main(
    const int* __restrict__ posX, const int* __restrict__ negX,
    const float* __restrict__ W_e, const float* __restrict__ W_ep,
    const float* __restrict__ W_r, const float* __restrict__ W_rp,
    float* __restrict__ partial_or_out, int nTriples, int atomicMode)
{
    const int tid  = threadIdx.x;
    const int wid  = tid >> 6;          // wave within block
    const int lane = tid & 63;
    const int l    = lane & 31;         // slice index within the 32-lane half
    const bool isNeg = (lane >= 32);
    const int* __restrict__ X = isNeg ? negX : posX;

    const int wavesPerBlock = blockDim.x >> 6;               // 4
    const int gw = blockIdx.x * wavesPerBlock + wid;         // global wave id
    const int nw = gridDim.x * wavesPerBlock;

    float acc = 0.0f;

    for (int b = gw; b < nTriples; b += nw) {
        const int h = X[b * 3 + 0];
        const int r = X[b * 3 + 1];
        const int t = X[b * 3 + 2];

        const size_t ho = (size_t)h * D + (size_t)l * 4;
        const size_t to = (size_t)t * D + (size_t)l * 4;
        const size_t ro = (size_t)r * D + (size_t)l * 4;

        // 6 independent coalesced gathers (512 B per 32-lane half per row)
        const float4 head  = *(const float4*)(W_e  + ho);
        const float4 headp = *(const float4*)(W_ep + ho);
        const float4 tail  = *(const float4*)(W_e  + to);
        const float4 tailp = *(const float4*)(W_ep + to);
        const float4 rel   = *(const float4*)(W_r  + ro);
        const float4 relp  = *(const float4*)(W_rp + ro);

        // per-lane partial dots
        float dh = headp.x * head.x + headp.y * head.y + headp.z * head.z + headp.w * head.w;
        float dt = tailp.x * tail.x + tailp.y * tail.y + tailp.z * tail.z + tailp.w * tail.w;

        // joint 32-lane reduction (masks <32 never cross the pos/neg halves)
        #pragma unroll
        for (int m = 1; m <= 16; m <<= 1) {
            dh += __shfl_xor(dh, m, 64);
            dt += __shfl_xor(dt, m, 64);
        }
        const float dd = dh - dt;

        // diff = (head + relp*dh) + rel - (tail + relp*dt) + EPS
        //      = head - tail + rel + relp*(dh - dt) + EPS
        float4 diff;
        diff.x = fmaf(relp.x, dd, head.x - tail.x + rel.x + EPS);
        diff.y = fmaf(relp.y, dd, head.y - tail.y + rel.y + EPS);
        diff.z = fmaf(relp.z, dd, head.z - tail.z + rel.z + EPS);
        diff.w = fmaf(relp.w, dd, head.w - tail.w + rel.w + EPS);

        float ss = diff.x * diff.x + diff.y * diff.y + diff.z * diff.z + diff.w * diff.w;
        #pragma unroll
        for (int m = 1; m <= 16; m <<= 1) ss += __shfl_xor(ss, m, 64);

        const float score = sqrtf(ss);                 // lanes 0-31: pos, 32-63: neg
        const float other = __shfl_xor(score, 32, 64); // swap halves

        if (lane == 0) acc += fmaxf(0.0f, score - other + MARGIN);
    }

    // block reduction of per-wave accumulators (deterministic order)
    __shared__ float sacc[8];
    if (lane == 0) sacc[wid] = acc;
    __syncthreads();
    if (tid == 0) {
        float s = 0.0f;
        for (int i = 0; i < wavesPerBlock; ++i) s += sacc[i];
        if (atomicMode) {
            atomicAdd(partial_or_out, s / (float)nTriples);
        } else {
            partial_or_out[blockIdx.x] = s;
        }
    }
}

__global__ void transd_reduce(const float* __restrict__ partial, int n,
                              float* __restrict__ out, int nTriples)
{
    __shared__ float s[256];
    float v = 0.0f;
    for (int i = threadIdx.x; i < n; i += 256) v += partial[i];
    s[threadIdx.x] = v;
    __syncthreads();
    for (int k = 128; k > 0; k >>= 1) {
        if ((int)threadIdx.x < k) s[threadIdx.x] += s[threadIdx.x + k];
        __syncthreads();
    }
    if (threadIdx.x == 0) out[0] = s[0] / (float)nTriples;
}

extern "C" void kernel_launch(void* const* d_in, const int* in_sizes, int n_in,
                              void* d_out, int out_size, void* d_ws, size_t ws_size,
                              hipStream_t stream) {
    const int*   posX = (const int*)d_in[0];
    const int*   negX = (const int*)d_in[1];
    const float* W_e  = (const float*)d_in[2];
    const float* W_ep = (const float*)d_in[3];
    const float* W_r  = (const float*)d_in[4];
    const float* W_rp = (const float*)d_in[5];
    float* out = (float*)d_out;

    const int nTriples = in_sizes[0] / 3;   // 131072
    const int NB = 2048;                    // 8 blocks/CU, 16 triple-pairs per wave

    if (ws_size >= (size_t)NB * sizeof(float)) {
        float* partial = (float*)d_ws;
        hipLaunchKernelGGL(transd_main, dim3(NB), dim3(256), 0, stream,
                           posX, negX, W_e, W_ep, W_r, W_rp, partial, nTriples, 0);
        hipLaunchKernelGGL(transd_reduce, dim3(1), dim3(256), 0, stream,
                           partial, NB, out, nTriples);
    } else {
        // fallback: atomic accumulation directly into d_out
        hipMemsetAsync(out, 0, sizeof(float), stream);
        hipLaunchKernelGGL(transd_main, dim3(NB), dim3(256), 0, stream,
                           posX, negX, W_e, W_ep, W_r, W_rp, out, nTriples, 1);
    }
}